// Round 4
// baseline (337.069 us; speedup 1.0000x reference)
//
#include <hip/hip_runtime.h>

// Temporal_Aggregation — fp32 fused kernel (MI355X gfx950).
//
// All inputs/outputs are float32 (per reference setup_inputs). Round-3 NaN
// proved the buffers are fp32, not bf16.
//
// Folded math:
//   WbigT[j=k*64+i][o] = sum_c Wlin[o][c] * Wconv[c][i][0][k]
//   biasC[o]           = sum_c Wlin[o][c] * bconv[c]
//   z[t][o]   = sum_j Vp[t + (j>>6)][j&63] * WbigT[j][o]   (Vp = T-zero-padded row)
//   out[t][o] = relu( z[t-1]+z[t]+z[t+1] (clipped) + m_t*biasC[o] + blin[o] ),
//   m_t = 3 - (t==0) - (t==23)
//
// Kept deliberately plain (no MFMA/ext-vector builtins): round-3 structure is
// the only binary proven to execute in this harness so far.

#define T_DIM 24

// d_ws floats: [0,12288) WbigT[192][64]; [12288,12352) biasC; [12352,12416) blinF

__global__ void prep_kernel(const float* Wconv, const float* bconv,
                            const float* Wlin, const float* blin, float* ws) {
    int idx = blockIdx.x * 256 + threadIdx.x;
    if (idx < 192 * 64) {
        int j = idx >> 6;        // 0..191
        int o = idx & 63;
        int k = j >> 6;          // conv tap 0..2
        int i = j & 63;          // conv input channel
        float acc = 0.0f;
        for (int c = 0; c < 64; ++c)
            acc += Wlin[o * 64 + c] * Wconv[c * 192 + i * 3 + k];
        ws[j * 64 + o] = acc;
    } else if (idx < 192 * 64 + 64) {
        int o = idx - 192 * 64;
        float acc = 0.0f;
        for (int c = 0; c < 64; ++c)
            acc += Wlin[o * 64 + c] * bconv[c];
        ws[12288 + o] = acc;
    } else if (idx < 192 * 64 + 128) {
        int o = idx - (192 * 64 + 64);
        ws[12352 + o] = blin[o];
    }
}

__global__ void fused_kernel(const float* value, const float* ws, float* out) {
    __shared__ __align__(16) float Vp[26 * 64];   // zero row + 24 rows + zero row
    __shared__ __align__(16) float zb[24 * 64];

    const int tid = threadIdx.x;           // 0..255
    const int o = tid & 63;                // output channel lane
    const int g = tid >> 6;                // wave id 0..3 -> t range [6g, 6g+6)
    const int row = blockIdx.x;            // (b*1024 + n), 0..16383

    // ---- stage value row (24x64 fp32) into padded LDS, float4 loads ----
    const float4* vsrc = (const float4*)(value + (long)row * 1536);
    for (int c4 = tid; c4 < 384; c4 += 256)
        *(float4*)(Vp + 64 + c4 * 4) = vsrc[c4];
    if (tid < 64) {
        Vp[tid] = 0.0f;
        Vp[25 * 64 + tid] = 0.0f;
    }
    __syncthreads();

    // ---- stage 1: z[t][o] for t in [6g, 6g+6) ----
    float acc0 = 0.0f, acc1 = 0.0f, acc2 = 0.0f;
    float acc3 = 0.0f, acc4 = 0.0f, acc5 = 0.0f;
    const int tbase = g * 6;
    for (int i = 0; i < 64; ++i) {
        float v0 = Vp[(tbase + 0) * 64 + i];
        float v1 = Vp[(tbase + 1) * 64 + i];
        float v2 = Vp[(tbase + 2) * 64 + i];
        float v3 = Vp[(tbase + 3) * 64 + i];
        float v4 = Vp[(tbase + 4) * 64 + i];
        float v5 = Vp[(tbase + 5) * 64 + i];
        float v6 = Vp[(tbase + 6) * 64 + i];
        float v7 = Vp[(tbase + 7) * 64 + i];
        // tap k=0
        float w = ws[(0 * 64 + i) * 64 + o];
        acc0 += w * v0; acc1 += w * v1; acc2 += w * v2;
        acc3 += w * v3; acc4 += w * v4; acc5 += w * v5;
        // tap k=1
        w = ws[(1 * 64 + i) * 64 + o];
        acc0 += w * v1; acc1 += w * v2; acc2 += w * v3;
        acc3 += w * v4; acc4 += w * v5; acc5 += w * v6;
        // tap k=2
        w = ws[(2 * 64 + i) * 64 + o];
        acc0 += w * v2; acc1 += w * v3; acc2 += w * v4;
        acc3 += w * v5; acc4 += w * v6; acc5 += w * v7;
    }
    zb[(tbase + 0) * 64 + o] = acc0;
    zb[(tbase + 1) * 64 + o] = acc1;
    zb[(tbase + 2) * 64 + o] = acc2;
    zb[(tbase + 3) * 64 + o] = acc3;
    zb[(tbase + 4) * 64 + o] = acc4;
    zb[(tbase + 5) * 64 + o] = acc5;
    __syncthreads();

    // ---- stage 2: band sum + bias + relu + float4 store ----
    for (int c4 = tid; c4 < 384; c4 += 256) {
        int t = c4 >> 4;                   // 0..23
        int ob = (c4 & 15) * 4;            // 0,4,..,60
        float4 s = *(const float4*)(zb + t * 64 + ob);
        float m = 3.0f;
        if (t > 0) {
            float4 p = *(const float4*)(zb + (t - 1) * 64 + ob);
            s.x += p.x; s.y += p.y; s.z += p.z; s.w += p.w;
        } else m -= 1.0f;
        if (t < 23) {
            float4 q = *(const float4*)(zb + (t + 1) * 64 + ob);
            s.x += q.x; s.y += q.y; s.z += q.z; s.w += q.w;
        } else m -= 1.0f;
        float4 bc = *(const float4*)(ws + 12288 + ob);
        float4 bl = *(const float4*)(ws + 12352 + ob);
        float4 r;
        r.x = s.x + m * bc.x + bl.x;
        r.y = s.y + m * bc.y + bl.y;
        r.z = s.z + m * bc.z + bl.z;
        r.w = s.w + m * bc.w + bl.w;
        r.x = fmaxf(r.x, 0.0f);
        r.y = fmaxf(r.y, 0.0f);
        r.z = fmaxf(r.z, 0.0f);
        r.w = fmaxf(r.w, 0.0f);
        *(float4*)(out + (long)row * 1536 + c4 * 4) = r;
    }
}

extern "C" void kernel_launch(void* const* d_in, const int* in_sizes, int n_in,
                              void* d_out, int out_size, void* d_ws, size_t ws_size,
                              hipStream_t stream) {
    const float* value = (const float*)d_in[0];
    const float* Wconv = (const float*)d_in[1];
    const float* bconv = (const float*)d_in[2];
    const float* Wlin  = (const float*)d_in[3];
    const float* blin  = (const float*)d_in[4];
    float* out = (float*)d_out;
    float* ws = (float*)d_ws;

    prep_kernel<<<49, 256, 0, stream>>>(Wconv, bconv, Wlin, blin, ws);
    fused_kernel<<<16384, 256, 0, stream>>>(value, ws, out);
}

// Round 5
// 210.764 us; speedup vs baseline: 1.5993x; 1.5993x over previous
//
#include <hip/hip_runtime.h>
#include <hip/hip_bf16.h>

// Temporal_Aggregation — MFMA bf16 fused kernel, fp32 I/O (MI355X gfx950).
//
// Folded math (validated numerically in round 4, fp32 VALU version):
//   Wbig[o][j=k*64+i] = sum_c Wlin[o][c]*Wconv[c][i][0][k]   (bf16 in ws)
//   biasC[o] = sum_c Wlin[o][c]*bconv[c]
//   z[t][o]  = sum_j Vp[t+(j>>6)][j&63] * Wbig[o][j]   (Vp = T-zero-padded row)
//   out[t][o] = relu( z[t-1]+z[t]+z[t+1] (clipped) + m_t*biasC[o] + blin[o] )
//   m_t = 3 - (t==0) - (t==23)
//
// NOTE (rounds 1-3 post-mortem): inputs/outputs are fp32. The rounds-1/2
// "untouched output" was NaN (fp32 read as bf16) clamped to 0 by fmaxf —
// the MFMA path itself compiles and runs fine.

typedef __attribute__((ext_vector_type(8))) short short8;
typedef __attribute__((ext_vector_type(8))) __bf16 bf16x8;
typedef __attribute__((ext_vector_type(4))) float f4;

#define R_ROWS 8                 // (b,n) rows per block
#define VP_STRIDE 72             // 64 + 8 pad shorts
#define V_ROW_ELEMS (26 * VP_STRIDE)        // 1872 shorts (pad row + 24 + pad row)
#define W_STRIDE 200             // 192 + 8 pad shorts
#define Z_STRIDE 68              // 64 + 4 pad floats

__device__ __forceinline__ unsigned short f2bfu(float f) {
    return __bfloat16_as_ushort(__float2bfloat16(f));
}

// ---- Kernel 1: fold conv+linear weights -------------------------------------
// ws bytes: [0,24576) Wbig bf16[64][192]; [24576,24832) biasC f32[64];
//           [24832,25088) blinF f32[64]
__global__ void prep_kernel(const float* __restrict__ Wconv,
                            const float* __restrict__ bconv,
                            const float* __restrict__ Wlin,
                            const float* __restrict__ blin,
                            __hip_bfloat16* __restrict__ wbig,
                            float* __restrict__ biasC,
                            float* __restrict__ blinF) {
    int idx = blockIdx.x * 256 + threadIdx.x;
    if (idx < 64 * 192) {
        int o = idx / 192;
        int j = idx - o * 192;
        int k = j >> 6;          // conv tap
        int i = j & 63;          // conv input channel
        float acc = 0.0f;
        for (int c = 0; c < 64; ++c)
            acc += Wlin[o * 64 + c] * Wconv[c * 192 + i * 3 + k];
        wbig[o * 192 + j] = __float2bfloat16(acc);
    } else if (idx < 64 * 192 + 64) {
        int o = idx - 64 * 192;
        float acc = 0.0f;
        for (int c = 0; c < 64; ++c)
            acc += Wlin[o * 64 + c] * bconv[c];
        biasC[o] = acc;
    } else if (idx < 64 * 192 + 128) {
        int o = idx - (64 * 192 + 64);
        blinF[o] = blin[o];
    }
}

// ---- Kernel 2: fused conv-GEMM (MFMA) + band sum + bias + relu --------------
__global__ void fused_kernel(const float* __restrict__ value,
                             const __hip_bfloat16* __restrict__ wbig,
                             const float* __restrict__ biasC,
                             const float* __restrict__ blinF,
                             float* __restrict__ out) {
    // [V tiles 29952 B][W 25600 B] = 55552 B; epilogue aliases zbuf (52224 B)
    __shared__ __align__(16) unsigned char smem[55552];
    short* Vlds = (short*)smem;                  // 8 x 26 x 72
    short* Wlds = (short*)(smem + 29952);        // 64 x 200
    float* zbuf = (float*)smem;                  // 192 x 68

    const int tid = threadIdx.x;
    const int wave = tid >> 6;
    const int lane = tid & 63;
    const int lane15 = lane & 15;
    const int quad = lane >> 4;
    const long base_row = (long)blockIdx.x * R_ROWS;

    // ---- stage value: 8 rows x 24x64 fp32 -> bf16 padded LDS ----
    for (int c4 = tid; c4 < 3072; c4 += 256) {     // float4 chunks
        int r = c4 / 384;
        int rem = c4 - r * 384;
        int t = rem >> 4;
        int d4 = (rem & 15) << 2;
        f4 v = *(const f4*)(value + (base_row + r) * 1536 + t * 64 + d4);
        ushort4 u;
        u.x = f2bfu(v.x); u.y = f2bfu(v.y); u.z = f2bfu(v.z); u.w = f2bfu(v.w);
        *(ushort4*)(Vlds + r * V_ROW_ELEMS + (t + 1) * VP_STRIDE + d4) = u;
    }
    if (tid < 128) {                               // zero rows 0 and 25
        int r = tid >> 4;
        int which = (tid >> 3) & 1;
        int d8 = (tid & 7) << 3;
        uint4 z; z.x = 0; z.y = 0; z.z = 0; z.w = 0;
        *(uint4*)(Vlds + r * V_ROW_ELEMS + which * (25 * VP_STRIDE) + d8) = z;
    }
    // ---- stage Wbig bf16 [64][192] -> LDS [64][200] ----
    const short* wsrc = (const short*)wbig;
    for (int c = tid; c < 1536; c += 256) {
        int n = c / 24;
        int k8 = (c - n * 24) << 3;
        *(uint4*)(Wlds + n * W_STRIDE + k8) = *(const uint4*)(wsrc + n * 192 + k8);
    }
    __syncthreads();

    // ---- MFMA: per wave 3 M-tiles (M=192), 4 N-tiles (N=64), K=192 ----
    f4 acc[3][4];
    #pragma unroll
    for (int a = 0; a < 3; ++a)
        #pragma unroll
        for (int b = 0; b < 4; ++b) {
            f4 zz = {0.f, 0.f, 0.f, 0.f};
            acc[a][b] = zz;
        }

    const int mt0 = wave * 3;
    int aoff[3];
    #pragma unroll
    for (int mt = 0; mt < 3; ++mt) {
        int m = (mt0 + mt) * 16 + lane15;          // GEMM row, m = r*24 + s
        int r = m / 24;
        int s = m - r * 24;
        aoff[mt] = r * V_ROW_ELEMS + s * VP_STRIDE;
    }
    const int k0 = quad * 8;
    #pragma unroll
    for (int ks = 0; ks < 6; ++ks) {
        int k = ks * 32 + k0;
        int ka = ((k >> 6) * VP_STRIDE) + (k & 63);
        bf16x8 bfr[4], afr[3];
        #pragma unroll
        for (int nt = 0; nt < 4; ++nt)
            bfr[nt] = __builtin_bit_cast(bf16x8,
                *(const short8*)(Wlds + nt * (16 * W_STRIDE) + lane15 * W_STRIDE + k));
        #pragma unroll
        for (int mt = 0; mt < 3; ++mt)
            afr[mt] = __builtin_bit_cast(bf16x8,
                *(const short8*)(Vlds + aoff[mt] + ka));
        #pragma unroll
        for (int mt = 0; mt < 3; ++mt)
            #pragma unroll
            for (int nt = 0; nt < 4; ++nt)
                acc[mt][nt] = __builtin_amdgcn_mfma_f32_16x16x32_bf16(
                    afr[mt], bfr[nt], acc[mt][nt], 0, 0, 0);
    }

    __syncthreads();
    // ---- spill z fp32 to LDS; C/D layout: col=lane&15, row=quad*4+reg [m89] ----
    #pragma unroll
    for (int mt = 0; mt < 3; ++mt) {
        int mbase = (mt0 + mt) * 16 + quad * 4;
        #pragma unroll
        for (int nt = 0; nt < 4; ++nt) {
            int o = nt * 16 + lane15;
            #pragma unroll
            for (int i = 0; i < 4; ++i)
                zbuf[(mbase + i) * Z_STRIDE + o] = acc[mt][nt][i];
        }
    }
    __syncthreads();

    // ---- epilogue: band sum + bias + relu + float4 stores ----
    for (int it = 0; it < 12; ++it) {
        int idx = it * 256 + tid;                  // 3072 quads
        int o4 = (idx & 15) << 2;
        int tt = (idx >> 4) % 24;
        int r = idx / 384;
        int zrow = r * 24 + tt;
        f4 s = *(const f4*)(zbuf + zrow * Z_STRIDE + o4);
        float m = 3.0f;
        if (tt > 0)  { f4 p = *(const f4*)(zbuf + (zrow - 1) * Z_STRIDE + o4); s += p; }
        else m -= 1.0f;
        if (tt < 23) { f4 q = *(const f4*)(zbuf + (zrow + 1) * Z_STRIDE + o4); s += q; }
        else m -= 1.0f;
        f4 bc = *(const f4*)(biasC + o4);
        f4 bl = *(const f4*)(blinF + o4);
        f4 v = s + m * bc + bl;
        v.x = fmaxf(v.x, 0.0f);
        v.y = fmaxf(v.y, 0.0f);
        v.z = fmaxf(v.z, 0.0f);
        v.w = fmaxf(v.w, 0.0f);
        long orow = (base_row + r) * 24 + tt;
        *(f4*)(out + orow * 64 + o4) = v;
    }
}

extern "C" void kernel_launch(void* const* d_in, const int* in_sizes, int n_in,
                              void* d_out, int out_size, void* d_ws, size_t ws_size,
                              hipStream_t stream) {
    const float* value = (const float*)d_in[0];
    const float* Wconv = (const float*)d_in[1];
    const float* bconv = (const float*)d_in[2];
    const float* Wlin  = (const float*)d_in[3];
    const float* blin  = (const float*)d_in[4];
    float* out = (float*)d_out;

    __hip_bfloat16* wbig = (__hip_bfloat16*)d_ws;
    float* biasC = (float*)((char*)d_ws + 24576);
    float* blinF = (float*)((char*)d_ws + 24832);

    prep_kernel<<<49, 256, 0, stream>>>(Wconv, bconv, Wlin, blin, wbig, biasC, blinF);
    fused_kernel<<<2048, 256, 0, stream>>>(value, wbig, biasC, blinF, out);
}

// Round 6
// 209.059 us; speedup vs baseline: 1.6123x; 1.0082x over previous
//
#include <hip/hip_runtime.h>
#include <hip/hip_bf16.h>

// Temporal_Aggregation — MFMA bf16, fp32 I/O, register band-sum (MI355X gfx950).
//
// Folded math (validated rounds 4/5):
//   Wbig[o][j=k*64+i] = sum_c Wlin[o][c]*Wconv[c][i][0][k]   (bf16 in ws)
//   z[t][o]  = sum_j Vp[t+(j>>6)][j&63] * Wbig[o][j]   (Vp = T-zero-padded row)
//   out[t][o] = relu( z[t-1]+z[t]+z[t+1] (clipped) + m_t*biasC[o] + blin[o] )
//
// Round-6 structure: LDS = V staging only (29952 B). W read as B-fragments
// straight from global (24.6 KB, L1-resident). Each wave's 3 M-tiles = 2 whole
// (b,n) rows, so the t+-1 band-sum is wave-local: done in registers via
// __shfl, C-fragments stored directly to global. 1 barrier instead of 3.

typedef __attribute__((ext_vector_type(8))) short short8;
typedef __attribute__((ext_vector_type(8))) __bf16 bf16x8;
typedef __attribute__((ext_vector_type(4))) float f4;

#define R_ROWS 8                 // (b,n) rows per block
#define VP_STRIDE 72             // 64 + 8 pad shorts
#define V_ROW_ELEMS (26 * VP_STRIDE)   // 1872 shorts (pad + 24 + pad)

__device__ __forceinline__ unsigned short f2bfu(float f) {
    return __bfloat16_as_ushort(__float2bfloat16(f));
}

// ---- Kernel 1: fold conv+linear weights -------------------------------------
// ws bytes: [0,24576) Wbig bf16[64][192]; [24576,24832) biasC f32[64];
//           [24832,25088) blinF f32[64]
__global__ void prep_kernel(const float* __restrict__ Wconv,
                            const float* __restrict__ bconv,
                            const float* __restrict__ Wlin,
                            const float* __restrict__ blin,
                            __hip_bfloat16* __restrict__ wbig,
                            float* __restrict__ biasC,
                            float* __restrict__ blinF) {
    __shared__ float Wl[4096];
    const int tid = threadIdx.x;
    for (int c = tid; c < 4096; c += 256) Wl[c] = Wlin[c];
    __syncthreads();
    int idx = blockIdx.x * 256 + tid;
    if (idx < 64 * 192) {
        int o = idx / 192;
        int j = idx - o * 192;
        int k = j >> 6;          // conv tap
        int i = j & 63;          // conv input channel
        float acc = 0.0f;
        for (int c = 0; c < 64; ++c)
            acc += Wl[o * 64 + c] * Wconv[c * 192 + i * 3 + k];
        wbig[o * 192 + j] = __float2bfloat16(acc);
    } else if (idx < 64 * 192 + 64) {
        int o = idx - 64 * 192;
        float acc = 0.0f;
        for (int c = 0; c < 64; ++c)
            acc += Wl[o * 64 + c] * bconv[c];
        biasC[o] = acc;
    } else if (idx < 64 * 192 + 128) {
        int o = idx - (64 * 192 + 64);
        blinF[o] = blin[o];
    }
}

// ---- Kernel 2: fused conv-GEMM (MFMA) + register band-sum + bias + relu -----
__global__ __launch_bounds__(256, 4) void fused_kernel(
    const float* __restrict__ value,
    const __hip_bfloat16* __restrict__ wbig,
    const float* __restrict__ biasC,
    const float* __restrict__ blinF,
    float* __restrict__ out) {
    __shared__ __align__(16) short Vlds[R_ROWS * V_ROW_ELEMS];   // 29952 B

    const int tid = threadIdx.x;
    const int wave = tid >> 6;
    const int lane = tid & 63;
    const int lane15 = lane & 15;
    const int quad = lane >> 4;
    const long base_row = (long)blockIdx.x * R_ROWS;

    // ---- stage value: 8 rows x 24x64 fp32 -> bf16 padded LDS ----
    for (int c4 = tid; c4 < 3072; c4 += 256) {     // float4 chunks
        int r = c4 / 384;
        int rem = c4 - r * 384;
        int t = rem >> 4;
        int d4 = (rem & 15) << 2;
        f4 v = *(const f4*)(value + (base_row + r) * 1536 + t * 64 + d4);
        ushort4 u;
        u.x = f2bfu(v.x); u.y = f2bfu(v.y); u.z = f2bfu(v.z); u.w = f2bfu(v.w);
        *(ushort4*)(Vlds + r * V_ROW_ELEMS + (t + 1) * VP_STRIDE + d4) = u;
    }
    if (tid < 128) {                               // zero pad rows 0 and 25
        int r = tid >> 4;
        int which = (tid >> 3) & 1;
        int d8 = (tid & 7) << 3;
        uint4 z; z.x = 0; z.y = 0; z.z = 0; z.w = 0;
        *(uint4*)(Vlds + r * V_ROW_ELEMS + which * (25 * VP_STRIDE) + d8) = z;
    }
    __syncthreads();

    // ---- MFMA: wave handles M=48 (3 tiles = rows 2*wave, 2*wave+1), N=64, K=192
    f4 acc[3][4];
    #pragma unroll
    for (int a = 0; a < 3; ++a)
        #pragma unroll
        for (int b = 0; b < 4; ++b) {
            f4 zz = {0.f, 0.f, 0.f, 0.f};
            acc[a][b] = zz;
        }

    const int mt0 = wave * 3;
    int aoff[3];
    #pragma unroll
    for (int mt = 0; mt < 3; ++mt) {
        int m = (mt0 + mt) * 16 + lane15;          // GEMM row, m = r*24 + s
        int r = m / 24;
        int s = m - r * 24;
        aoff[mt] = r * V_ROW_ELEMS + s * VP_STRIDE;
    }
    const short* wsrc = (const short*)wbig;        // [64][192]
    const int k0 = quad * 8;
    #pragma unroll
    for (int ks = 0; ks < 6; ++ks) {
        int k = ks * 32 + k0;
        int ka = ((k >> 6) * VP_STRIDE) + (k & 63);
        bf16x8 bfr[4], afr[3];
        #pragma unroll
        for (int nt = 0; nt < 4; ++nt)             // B straight from global (L1)
            bfr[nt] = __builtin_bit_cast(bf16x8,
                *(const short8*)(wsrc + (nt * 16 + lane15) * 192 + k));
        #pragma unroll
        for (int mt = 0; mt < 3; ++mt)
            afr[mt] = __builtin_bit_cast(bf16x8,
                *(const short8*)(Vlds + aoff[mt] + ka));
        #pragma unroll
        for (int mt = 0; mt < 3; ++mt)
            #pragma unroll
            for (int nt = 0; nt < 4; ++nt)
                acc[mt][nt] = __builtin_amdgcn_mfma_f32_16x16x32_bf16(
                    afr[mt], bfr[nt], acc[mt][nt], 0, 0, 0);
    }

    // ---- epilogue: wave-local band sum via shuffles, store from fragments ----
    // C/D: col = lane&15, row16 = quad*4 + i  [m89]. Wave row = mt*16+row16,
    // t = waverow % 24, r_rel = waverow / 24.
    float b3[4], b2[4];
    #pragma unroll
    for (int nt = 0; nt < 4; ++nt) {
        int o = nt * 16 + lane15;
        float bc = biasC[o];
        float bl = blinF[o];
        b3[nt] = 3.0f * bc + bl;
        b2[nt] = 2.0f * bc + bl;
    }
    const int srcP = (lane + 48) & 63;             // quad-1 lane / quad3-of-prev-tile
    const int srcN = (lane + 16) & 63;             // quad+1 lane / quad0-of-next-tile
    #pragma unroll
    for (int mt = 0; mt < 3; ++mt) {
        const int mtp = (mt > 0) ? mt - 1 : 0;     // cross-tile refs (masked when invalid)
        const int mtn = (mt < 2) ? mt + 1 : 2;
        #pragma unroll
        for (int nt = 0; nt < 4; ++nt) {
            float pin = __shfl(acc[mt][nt][3], srcP, 64);
            float pxr = __shfl(acc[mtp][nt][3], srcP, 64);
            float nin = __shfl(acc[mt][nt][0], srcN, 64);
            float nxr = __shfl(acc[mtn][nt][0], srcN, 64);
            float prev0 = (quad == 0) ? pxr : pin;
            float next3 = (quad == 3) ? nxr : nin;
            #pragma unroll
            for (int i = 0; i < 4; ++i) {
                int tq = mt * 16 + quad * 4 + i;   // wave-relative row 0..47
                int rr = (tq >= 24) ? 1 : 0;
                int t = tq - rr * 24;
                float s = acc[mt][nt][i];
                float prev = (i > 0) ? acc[mt][nt][i - 1] : prev0;
                float next = (i < 3) ? acc[mt][nt][i + 1] : next3;
                if (t > 0)  s += prev;
                if (t < 23) s += next;
                float bias = (t == 0 || t == 23) ? b2[nt] : b3[nt];
                float r = fmaxf(s + bias, 0.0f);
                long addr = ((base_row + 2 * wave + rr) * 24 + t) * 64
                            + nt * 16 + lane15;
                out[addr] = r;
            }
        }
    }
}

extern "C" void kernel_launch(void* const* d_in, const int* in_sizes, int n_in,
                              void* d_out, int out_size, void* d_ws, size_t ws_size,
                              hipStream_t stream) {
    const float* value = (const float*)d_in[0];
    const float* Wconv = (const float*)d_in[1];
    const float* bconv = (const float*)d_in[2];
    const float* Wlin  = (const float*)d_in[3];
    const float* blin  = (const float*)d_in[4];
    float* out = (float*)d_out;

    __hip_bfloat16* wbig = (__hip_bfloat16*)d_ws;
    float* biasC = (float*)((char*)d_ws + 24576);
    float* blinF = (float*)((char*)d_ws + 24832);

    prep_kernel<<<49, 256, 0, stream>>>(Wconv, bconv, Wlin, blin, wbig, biasC, blinF);
    fused_kernel<<<2048, 256, 0, stream>>>(value, wbig, biasC, blinF, out);
}

// Round 7
// 200.097 us; speedup vs baseline: 1.6845x; 1.0448x over previous
//
#include <hip/hip_runtime.h>
#include <hip/hip_bf16.h>

// Temporal_Aggregation — persistent pipelined MFMA kernel (MI355X gfx950).
//
// Folded math (validated rounds 4-6):
//   Wbig[o][j=k*64+i] = sum_c Wlin[o][c]*Wconv[c][i][0][k]   (bf16 in ws)
//   z[t][o]  = sum_j Vp[t+(j>>6)][j&63] * Wbig[o][j]   (Vp = T-zero-padded row)
//   out[t][o] = relu( z[t-1]+z[t]+z[t+1] (clipped) + m_t*biasC[o] + blin[o] )
//
// Round-7 structure (fixing round-6 latency-boundness: all pipes <25% busy):
//  - 512 persistent blocks (2/CU, zero tail), 4 groups of 8 rows each.
//  - N-split: wave owns one 16-col N-tile for all 12 M-tiles; its 6 B-fragments
//    live in 24 VGPRs, loaded once -> K-loop is pure LDS+MFMA (no vmcnt inside,
//    so prefetch loads stay in flight across the loop).
//  - Double-buffered V LDS + register prefetch of next group; 1 barrier/iter.
//  - Wave-local register band-sum epilogue (round-6 shuffle scheme, 12 tiles).

typedef __attribute__((ext_vector_type(8))) short short8;
typedef __attribute__((ext_vector_type(8))) __bf16 bf16x8;
typedef __attribute__((ext_vector_type(4))) float f4;

#define R_ROWS 8                 // rows per group
#define GROUPS 4                 // groups per block
#define VP_STRIDE 72             // 64 + 8 pad shorts
#define V_ROW_ELEMS (26 * VP_STRIDE)   // 1872 shorts (pad + 24 + pad)

__device__ __forceinline__ unsigned short f2bfu(float f) {
    return __bfloat16_as_ushort(__float2bfloat16(f));
}

// ---- Kernel 1: fold conv+linear weights -------------------------------------
// ws bytes: [0,24576) Wbig bf16[64][192]; [24576,24832) biasC f32[64];
//           [24832,25088) blinF f32[64]
__global__ void prep_kernel(const float* __restrict__ Wconv,
                            const float* __restrict__ bconv,
                            const float* __restrict__ Wlin,
                            const float* __restrict__ blin,
                            __hip_bfloat16* __restrict__ wbig,
                            float* __restrict__ biasC,
                            float* __restrict__ blinF) {
    __shared__ float Wl[4096];
    const int tid = threadIdx.x;
    for (int c = tid; c < 4096; c += 256) Wl[c] = Wlin[c];
    __syncthreads();
    int idx = blockIdx.x * 256 + tid;
    if (idx < 64 * 192) {
        int o = idx / 192;
        int j = idx - o * 192;
        int k = j >> 6;
        int i = j & 63;
        float acc = 0.0f;
        for (int c = 0; c < 64; ++c)
            acc += Wl[o * 64 + c] * Wconv[c * 192 + i * 3 + k];
        wbig[o * 192 + j] = __float2bfloat16(acc);
    } else if (idx < 64 * 192 + 64) {
        int o = idx - 64 * 192;
        float acc = 0.0f;
        for (int c = 0; c < 64; ++c)
            acc += Wl[o * 64 + c] * bconv[c];
        biasC[o] = acc;
    } else if (idx < 64 * 192 + 128) {
        int o = idx - (64 * 192 + 64);
        blinF[o] = blin[o];
    }
}

// ---- Kernel 2: persistent pipelined conv-GEMM + band sum + bias + relu ------
__global__ __launch_bounds__(256, 2) void fused_kernel(
    const float* __restrict__ value,
    const __hip_bfloat16* __restrict__ wbig,
    const float* __restrict__ biasC,
    const float* __restrict__ blinF,
    float* __restrict__ out) {
    __shared__ __align__(16) short Vlds[2][R_ROWS * V_ROW_ELEMS];  // 2 x 29952 B

    const int tid = threadIdx.x;
    const int wave = tid >> 6;            // = N-tile index
    const int lane = tid & 63;
    const int lane15 = lane & 15;
    const int quad = lane >> 4;
    const long block_row0 = (long)blockIdx.x * (R_ROWS * GROUPS);

    // per-thread fixed staging offsets (12 float4 chunks per group)
    int goff[12], loff[12];
    #pragma unroll
    for (int j = 0; j < 12; ++j) {
        int c4 = tid + 256 * j;           // 0..3071
        int r = c4 / 384;
        int rem = c4 - r * 384;
        int t = rem >> 4;
        int d4 = (rem & 15) << 2;
        goff[j] = r * 1536 + t * 64 + d4;
        loff[j] = r * V_ROW_ELEMS + (t + 1) * VP_STRIDE + d4;
    }
    // zero the pad rows of both buffers (never overwritten after)
    if (tid < 128) {
        int r = tid >> 4;
        int which = (tid >> 3) & 1;
        int d8 = (tid & 7) << 3;
        uint4 z; z.x = 0; z.y = 0; z.z = 0; z.w = 0;
        *(uint4*)(&Vlds[0][0] + r * V_ROW_ELEMS + which * (25 * VP_STRIDE) + d8) = z;
        *(uint4*)(&Vlds[1][0] + r * V_ROW_ELEMS + which * (25 * VP_STRIDE) + d8) = z;
    }

    // ---- B fragments for this wave's N-tile: 6 x 16B, held in VGPRs ----
    const short* wsrc = (const short*)wbig;
    const int k0 = quad * 8;
    bf16x8 breg[6];
    #pragma unroll
    for (int ks = 0; ks < 6; ++ks)
        breg[ks] = __builtin_bit_cast(bf16x8,
            *(const short8*)(wsrc + (wave * 16 + lane15) * 192 + ks * 32 + k0));

    // ---- prologue: load + stage group 0 into buffer 0 ----
    f4 pre[12];
    {
        const float* vb = value + block_row0 * 1536;
        #pragma unroll
        for (int j = 0; j < 12; ++j)
            pre[j] = *(const f4*)(vb + goff[j]);
        #pragma unroll
        for (int j = 0; j < 12; ++j) {
            ushort4 u;
            u.x = f2bfu(pre[j].x); u.y = f2bfu(pre[j].y);
            u.z = f2bfu(pre[j].z); u.w = f2bfu(pre[j].w);
            *(ushort4*)(&Vlds[0][0] + loff[j]) = u;
        }
    }
    __syncthreads();

    // fixed A-fragment offsets (per M-tile)
    int aoff[12];
    #pragma unroll
    for (int mt = 0; mt < 12; ++mt) {
        int m = mt * 16 + lane15;          // GEMM row, m = r*24 + s
        int r = m / 24;
        int s = m - r * 24;
        aoff[mt] = r * V_ROW_ELEMS + s * VP_STRIDE;
    }

    // bias precompute for this wave's 16 columns
    const int o = wave * 16 + lane15;
    const float bc = biasC[o];
    const float bl = blinF[o];
    const float b3 = 3.0f * bc + bl;
    const float b2 = 2.0f * bc + bl;
    const int srcP = (lane + 48) & 63;
    const int srcN = (lane + 16) & 63;

    int p = 0;
    for (int g = 0; g < GROUPS; ++g) {
        // issue prefetch for next group (stays in flight through the K-loop)
        if (g + 1 < GROUPS) {
            const float* vb = value + (block_row0 + (long)(g + 1) * R_ROWS) * 1536;
            #pragma unroll
            for (int j = 0; j < 12; ++j)
                pre[j] = *(const f4*)(vb + goff[j]);
        }

        // ---- K-loop: 12 M-tiles x this wave's N-tile, K=192, pure LDS+MFMA ----
        const short* Vcur = &Vlds[p][0];
        f4 acc[12];
        #pragma unroll
        for (int mt = 0; mt < 12; ++mt) {
            f4 zz = {0.f, 0.f, 0.f, 0.f};
            acc[mt] = zz;
        }
        #pragma unroll
        for (int ks = 0; ks < 6; ++ks) {
            int k = ks * 32 + k0;
            int ka = ((k >> 6) * VP_STRIDE) + (k & 63);
            #pragma unroll
            for (int mt = 0; mt < 12; ++mt) {
                bf16x8 a = __builtin_bit_cast(bf16x8,
                    *(const short8*)(Vcur + aoff[mt] + ka));
                acc[mt] = __builtin_amdgcn_mfma_f32_16x16x32_bf16(
                    a, breg[ks], acc[mt], 0, 0, 0);
            }
        }

        // ---- epilogue: wave-local band sum (shuffles), bias, relu, store ----
        // C/D layout: col = lane&15, row16 = quad*4 + i  [m89]
        const long grow0 = block_row0 + (long)g * R_ROWS;
        #pragma unroll
        for (int mt = 0; mt < 12; ++mt) {
            const int mtp = (mt > 0) ? mt - 1 : 0;
            const int mtn = (mt < 11) ? mt + 1 : 11;
            float pin = __shfl(acc[mt][3], srcP, 64);
            float pxr = __shfl(acc[mtp][3], srcP, 64);
            float nin = __shfl(acc[mt][0], srcN, 64);
            float nxr = __shfl(acc[mtn][0], srcN, 64);
            float prev0 = (quad == 0) ? pxr : pin;
            float next3 = (quad == 3) ? nxr : nin;
            #pragma unroll
            for (int i = 0; i < 4; ++i) {
                int rowq = mt * 16 + quad * 4 + i;  // 0..191
                int rr = rowq / 24;
                int t = rowq - rr * 24;
                float s = acc[mt][i];
                float prev = (i > 0) ? acc[mt][i - 1] : prev0;
                float next = (i < 3) ? acc[mt][i + 1] : next3;
                if (t > 0)  s += prev;
                if (t < 23) s += next;
                float r = fmaxf(s + ((t == 0 || t == 23) ? b2 : b3), 0.0f);
                out[((grow0 + rr) * 24 + t) * 64 + o] = r;
            }
        }

        // ---- stage next group into the other buffer ----
        if (g + 1 < GROUPS) {
            short* Vnxt = &Vlds[p ^ 1][0];
            #pragma unroll
            for (int j = 0; j < 12; ++j) {
                ushort4 u;
                u.x = f2bfu(pre[j].x); u.y = f2bfu(pre[j].y);
                u.z = f2bfu(pre[j].z); u.w = f2bfu(pre[j].w);
                *(ushort4*)(Vnxt + loff[j]) = u;
            }
            __syncthreads();
        }
        p ^= 1;
    }
}

extern "C" void kernel_launch(void* const* d_in, const int* in_sizes, int n_in,
                              void* d_out, int out_size, void* d_ws, size_t ws_size,
                              hipStream_t stream) {
    const float* value = (const float*)d_in[0];
    const float* Wconv = (const float*)d_in[1];
    const float* bconv = (const float*)d_in[2];
    const float* Wlin  = (const float*)d_in[3];
    const float* blin  = (const float*)d_in[4];
    float* out = (float*)d_out;

    __hip_bfloat16* wbig = (__hip_bfloat16*)d_ws;
    float* biasC = (float*)((char*)d_ws + 24576);
    float* blinF = (float*)((char*)d_ws + 24832);

    prep_kernel<<<49, 256, 0, stream>>>(Wconv, bconv, Wlin, blin, wbig, biasC, blinF);
    // 16384 rows / (8 rows * 4 groups) = 512 persistent blocks (2 per CU)
    fused_kernel<<<512, 256, 0, stream>>>(value, wbig, biasC, blinF, out);
}